// Round 5
// baseline (681.734 us; speedup 1.0000x reference)
//
#include <hip/hip_runtime.h>
#include <math.h>

#define N    257     // state dim
#define AP   258     // doubles per A row (cols 0..256 = S, col 257 = rhs)
#define MM   128     // rotation pairs
#define LL   512     // seq length
#define BB   4       // batch
#define NB   32      // panel width
#define NBLK 16      // blocks in the fused LU kernel (all co-resident)

// ws byte layout:
#define A_BYTE    0         // double[257*258] = 530448
#define W0_BYTE   530448    // float[257]  -> ends 531476
#define CXY_BYTE  531488    // float[4096] -> ends 547872
#define PW_BYTE   547904    // double[32*257] = 65792 -> ends 613696
#define U12_BYTE  613696    // double[32*226] = 57856 -> ends 671552
#define ST_BYTE   671552    // float[257*257] = 264196 -> ends 935748
#define BAR_BYTE  935752    // 2 x u32 barrier state -> ends 935760
// total ~936 KB (ws >= 1.31 MB)

// ---------------------------------------------------------------------------
// device-scope sense-reversing grid barrier (16 co-resident blocks).
// cnt/gen are zeroed by scan_kernel each iteration (ws gets poisoned between
// iters). g is ACQUIRE-loaded BEFORE the arrival fetch_add so a late reader
// cannot miss the generation bump. Spin capped so a bug FAILS, not hangs.
// ---------------------------------------------------------------------------
__device__ __forceinline__ void grid_sync(unsigned* cnt, unsigned* gen) {
  __syncthreads();
  if (threadIdx.x == 0) {
    __threadfence();
    const unsigned g = __hip_atomic_load(gen, __ATOMIC_ACQUIRE, __HIP_MEMORY_SCOPE_AGENT);
    const unsigned a = __hip_atomic_fetch_add(cnt, 1u, __ATOMIC_ACQ_REL, __HIP_MEMORY_SCOPE_AGENT);
    if (a == NBLK - 1) {
      __hip_atomic_store(cnt, 0u, __ATOMIC_RELAXED, __HIP_MEMORY_SCOPE_AGENT);
      __hip_atomic_fetch_add(gen, 1u, __ATOMIC_ACQ_REL, __HIP_MEMORY_SCOPE_AGENT);
    } else {
      long spins = 0;
      while (__hip_atomic_load(gen, __ATOMIC_ACQUIRE, __HIP_MEMORY_SCOPE_AGENT) == g) {
        __builtin_amdgcn_s_sleep(2);
        if (++spins > 20000000L) break;   // fail visibly, never hang
      }
    }
    __threadfence();
  }
  __syncthreads();
}

// ---------------------------------------------------------------------------
// prefix sums of x[b,:,comp] + zero the grid-barrier state for this iteration
// ---------------------------------------------------------------------------
__global__ __launch_bounds__(512) void scan_kernel(const float* __restrict__ x,
                                                   void* __restrict__ wsv) {
  const int tid  = threadIdx.x;
  if (tid == 0) {
    unsigned* bar = (unsigned*)((char*)wsv + BAR_BYTE);
    bar[0] = 0u; bar[1] = 0u;
  }
  const int wave = tid >> 6, lane = tid & 63;
  const int b    = wave >> 1, comp = wave & 1;

  const float* xp = x + ((size_t)b * LL) * 2 + comp;
  double loc[8];
  double run = 0.0;
  #pragma unroll
  for (int e = 0; e < 8; ++e) {
    run += (double)xp[(lane * 8 + e) * 2];
    loc[e] = run;
  }
  double tot = run;
  #pragma unroll
  for (int off = 1; off < 64; off <<= 1) {
    const double o = __shfl_up(tot, off);
    if (lane >= off) tot += o;
  }
  const double excl = tot - run;
  float* cp = (float*)((char*)wsv + CXY_BYTE) + ((size_t)b * LL) * 2 + comp;
  #pragma unroll
  for (int e = 0; e < 8; ++e)
    cp[(lane * 8 + e) * 2] = (float)(excl + loc[e]);
}

// ---------------------------------------------------------------------------
// fused LU solve: stage + 8 x (panel factor | rank-32 update) + finish,
// one dispatch, 16 blocks x 512 threads, grid_sync between phases.
// Phase bodies are the round-3/4 verified ones (factor: row-parallel Jordan,
// fully unrolled; update: 32x64 tiles, re-tiled for 512 thr at 1 row x 4 col).
// LDS: one 128 KB block aliased per-phase.
// ---------------------------------------------------------------------------
__global__ __launch_bounds__(512) void lu_kernel(const float* __restrict__ S,
                                                 const float* __restrict__ z0,
                                                 void* __restrict__ wsv) {
  __shared__ double SM[16000];            // 128000 B
  double* A    = (double*)((char*)wsv + A_BYTE);
  double* Pw   = (double*)((char*)wsv + PW_BYTE);
  double* U12w = (double*)((char*)wsv + U12_BYTE);
  float*  St   = (float*)((char*)wsv + ST_BYTE);
  float*  w0f  = (float*)((char*)wsv + W0_BYTE);
  unsigned* bar = (unsigned*)((char*)wsv + BAR_BYTE);
  unsigned* cnt = bar, * gen = bar + 1;

  const int tid = threadIdx.x;
  const int bid = blockIdx.x;
  const int gid = bid * 512 + tid;

  // ================= phase 0: stage A = [S | z0] fp64, St = S^T fp32 ========
  for (int idx = gid; idx < N * N + N; idx += NBLK * 512) {
    if (idx < N * N) {
      const int i = idx / N, j = idx - i * N;
      A[(size_t)i * AP + j] = (double)S[idx];
      St[idx] = S[j * N + i];            // St[d][i] = S[i][d]
    } else {
      const int r = idx - N * N;
      A[(size_t)r * AP + N] = (double)z0[r];
    }
  }
  grid_sync(cnt, gen);

  // ================= 8 panels =============================================
  for (int p = 0; p < 8; ++p) {
    const int k0  = p * NB;
    const int ct  = k0 + NB;
    const int tc2 = 258 - ct;            // trailing cols incl rhs

    // ---- factor phase: block 0 only (round-3 body) ----
    if (bid == 0) {
      double (*P)[NB + 1]   = (double(*)[NB + 1])SM;            // 257*33 = 8481
      double (*u_s)[NB + 1] = (double(*)[NB + 1])(SM + 8481);   // 226*33 = 7458
      double* pinv          = SM + 8481 + 7458;                 // 32

      for (int flat = tid; flat < N * 16; flat += 512) {
        const int i  = flat >> 4;
        const int cp = (flat & 15) * 2;
        const double2 v = *(const double2*)&A[(size_t)i * AP + k0 + cp];
        P[i][cp]     = v.x;
        P[i][cp + 1] = v.y;
      }
      if (tid < tc2) {
        #pragma unroll
        for (int jr = 0; jr < NB; ++jr)
          u_s[tid][jr] = A[(size_t)(k0 + jr) * AP + ct + tid];
      }
      __syncthreads();
      if (tid == 0) pinv[0] = 1.0 / P[k0][0];
      __syncthreads();

      #pragma unroll
      for (int j = 0; j < NB; ++j) {
        const int pr = k0 + j;
        if (tid < N && (tid < k0 || tid > pr)) {
          const double f = P[tid][j] * pinv[j];
          #pragma unroll
          for (int j2 = j + 1; j2 < NB; ++j2)
            P[tid][j2] -= f * P[pr][j2];
          P[tid][j] = f;
          if (tid == pr + 1 && j + 1 < NB)
            pinv[j + 1] = 1.0 / P[tid][j + 1];
        }
        __syncthreads();
      }

      if (tid < N) {
        #pragma unroll
        for (int t = 0; t < NB; ++t)
          Pw[(size_t)t * N + tid] = P[tid][t];
      }
      for (int flat = tid; flat < NB * NB; flat += 512) {
        const int r = flat >> 5, c = flat & 31;
        A[(size_t)(k0 + r) * AP + k0 + c] = P[k0 + r][c];
      }

      if (tid < tc2) {
        #pragma unroll
        for (int jr = 1; jr < NB; ++jr) {
          double vv = u_s[tid][jr];
          #pragma unroll
          for (int t = 0; t < jr; ++t)
            vv -= P[k0 + jr][t] * u_s[tid][t];
          u_s[tid][jr] = vv;
        }
        #pragma unroll
        for (int jr = 0; jr < NB; ++jr) {
          const double vv = u_s[tid][jr];
          U12w[jr * 226 + tid] = vv;
          A[(size_t)(k0 + jr) * AP + ct + tid] = vv;
        }
      }
    }
    grid_sync(cnt, gen);

    // ---- update phase: all blocks, tiles 32 rows x 64 cols ----
    {
      double (*Pl)[NB + 1] = (double(*)[NB + 1])SM;             // 32*33 = 1056
      double (*Ul)[66]     = (double(*)[66])(SM + 1056);        // 32*66 = 2112
      const int nct    = (tc2 + 63) / 64;
      const int ntiles = 8 * nct;
      for (int t0 = bid; t0 < ntiles; t0 += NBLK) {
        const int rb0 = (t0 / nct) * 32;
        const int c0  = (t0 % nct) * 64;

        for (int i = tid; i < 32 * 32; i += 512) {
          const int t = i >> 5, rr = i & 31;
          const int rb = rb0 + rr;
          const int gr = (rb < k0) ? rb : rb + NB;
          Pl[t][rr] = (rb < 225) ? Pw[(size_t)t * N + gr] : 0.0;
        }
        for (int i = tid; i < 32 * 64; i += 512) {
          const int t = i >> 6, c = i & 63;
          Ul[t][c] = (c0 + c < tc2) ? U12w[t * 226 + c0 + c] : 0.0;
        }
        __syncthreads();

        const int tr  = tid >> 4;          // 0..31 (row in tile)
        const int tcx = (tid & 15) * 4;    // col group
        const int rb  = rb0 + tr;
        const int gr  = (rb < k0) ? rb : rb + NB;
        double acc[4];
        #pragma unroll
        for (int c = 0; c < 4; ++c)
          acc[c] = (rb < 225 && (c0 + tcx + c) < tc2)
                 ? A[(size_t)gr * AP + ct + c0 + tcx + c] : 0.0;
        #pragma unroll
        for (int t = 0; t < NB; ++t) {
          const double p0 = Pl[t][tr];
          const double2 u0 = *(const double2*)&Ul[t][tcx];
          const double2 u1 = *(const double2*)&Ul[t][tcx + 2];
          acc[0] -= p0 * u0.x; acc[1] -= p0 * u0.y;
          acc[2] -= p0 * u1.x; acc[3] -= p0 * u1.y;
        }
        #pragma unroll
        for (int c = 0; c < 4; ++c)
          if (rb < 225 && (c0 + tcx + c) < tc2)
            A[(size_t)gr * AP + ct + c0 + tcx + c] = acc[c];
        __syncthreads();                   // LDS reused next tile
      }
    }
    grid_sync(cnt, gen);
  }

  // ================= finish: block 0, 8 parallel 32-step back-substs ========
  if (bid == 0) {
    double* xs = SM;                       // 257
    double* rr = SM + 264;                 // 256
    if (tid == 0) xs[256] = A[256 * AP + 257] / A[256 * AP + 256];
    __syncthreads();
    const double x256 = xs[256];
    if (tid < 256) rr[tid] = A[tid * AP + 257] - A[tid * AP + 256] * x256;
    __syncthreads();
    const int fk0 = tid & ~31;
    const int fs  = tid & 31;
    for (int j = 31; j >= 0; --j) {
      if (tid < 256 && fs == j)
        xs[fk0 + j] = rr[fk0 + j] / A[(fk0 + j) * AP + (fk0 + j)];
      __syncthreads();
      if (tid < 256 && fs < j)
        rr[fk0 + fs] -= A[(fk0 + fs) * AP + (fk0 + j)] * xs[fk0 + j];
      __syncthreads();
    }
    if (tid < 256) w0f[tid] = (float)xs[tid];
    if (tid == 0)  w0f[256] = (float)xs[256];
  }
}

// ---------------------------------------------------------------------------
// combine: out[(b,l), i] = sum_d St[d, i] * W[(b,l), d]   (round-4 version)
// ---------------------------------------------------------------------------
#define NL 8
__global__ __launch_bounds__(320) void combine_kernel(const float* __restrict__ S,
                                                      const float* __restrict__ om,
                                                      const void* __restrict__ wsv,
                                                      float* __restrict__ out) {
  const int tid = threadIdx.x;
  const int b  = blockIdx.y;
  const int l0 = blockIdx.x * NL;
  const float* w0  = (const float*)((const char*)wsv + W0_BYTE);
  const float* cxy = (const float*)((const char*)wsv + CXY_BYTE);
  const float* St  = (const float*)((const char*)wsv + ST_BYTE);
  __shared__ __align__(16) float Wl[N][NL];
  __shared__ float omsh[2 * MM];
  __shared__ float cxs[NL], cys[NL];

  for (int idx = tid; idx < 2 * MM; idx += 320) omsh[idx] = om[idx];
  if (tid < NL) {
    cxs[tid] = cxy[((size_t)(b * LL) + l0 + tid) * 2];
    cys[tid] = cxy[((size_t)(b * LL) + l0 + tid) * 2 + 1];
  }
  __syncthreads();

  for (int idx = tid; idx < NL * N; idx += 320) {
    const int d = idx >> 3;
    const int r = idx & 7;
    float v;
    if (d == 0) {
      v = w0[0];
    } else {
      const int m = (d - 1) >> 1;
      const int pq = 2 * m + 1;
      const float t = cxs[r] * omsh[2 * m] + cys[r] * omsh[2 * m + 1];
      float s, c;
      sincosf(t, &s, &c);
      const float a0 = w0[pq], a1 = w0[pq + 1];
      v = (d & 1) ? (c * a0 - s * a1) : (s * a0 + c * a1);
    }
    Wl[d][r] = v;
  }
  __syncthreads();

  const int i = tid;
  if (i < N) {
    float acc[NL];
    #pragma unroll
    for (int r = 0; r < NL; ++r) acc[r] = 0.0f;
    #pragma unroll 8
    for (int d = 0; d < N; ++d) {
      const float stv = St[(size_t)d * N + i];
      const float4 wa = *(const float4*)&Wl[d][0];
      const float4 wb = *(const float4*)&Wl[d][4];
      acc[0] += stv * wa.x; acc[1] += stv * wa.y;
      acc[2] += stv * wa.z; acc[3] += stv * wa.w;
      acc[4] += stv * wb.x; acc[5] += stv * wb.y;
      acc[6] += stv * wb.z; acc[7] += stv * wb.w;
    }
    const size_t base = (size_t)(b * LL + l0) * N + i;
    #pragma unroll
    for (int r = 0; r < NL; ++r) out[base + (size_t)r * N] = acc[r];
    if (l0 + NL == LL) {
      out[(size_t)BB * LL * N + (size_t)b * N + i] = acc[NL - 1];
    }
  }
}

extern "C" void kernel_launch(void* const* d_in, const int* in_sizes, int n_in,
                              void* d_out, int out_size, void* d_ws, size_t ws_size,
                              hipStream_t stream) {
  const float* x  = (const float*)d_in[0];   // (B, L, 2)
  const float* z0 = (const float*)d_in[1];   // (D,)
  const float* om = (const float*)d_in[2];   // (M, 2)
  const float* S  = (const float*)d_in[3];   // (D, D)
  float* out = (float*)d_out;                // outputs (B,L,D) then z_final (B,D)

  hipLaunchKernelGGL(scan_kernel, dim3(1),    dim3(512), 0, stream, x, d_ws);
  hipLaunchKernelGGL(lu_kernel,   dim3(NBLK), dim3(512), 0, stream, S, z0, d_ws);
  hipLaunchKernelGGL(combine_kernel, dim3(LL / NL, BB), dim3(320), 0, stream, S, om, d_ws, out);
}

// Round 6
// 359.919 us; speedup vs baseline: 1.8941x; 1.8941x over previous
//
#include <hip/hip_runtime.h>
#include <math.h>

#define N    257     // state dim
#define AP   258     // doubles per A row (cols 0..256 = S, col 257 = rhs)
#define MM   128     // rotation pairs
#define LL   512     // seq length
#define BB   4       // batch
#define NB   32      // panel width

// ws byte layout:
#define A_BYTE    0         // double[257*258] = 530448
#define W0_BYTE   530448    // float[257]  -> ends 531476
#define CXY_BYTE  531488    // float[4096] -> ends 547872
#define PW_BYTE   547904    // double[32*257] = 65792 -> ends 613696
#define U12_BYTE  613696    // double[32*226] = 57856 -> ends 671552
#define ST_BYTE   671552    // float[257*257] = 264196 -> ends 935748
// total ~936 KB (ws >= 1.31 MB)

// ---------------------------------------------------------------------------
// prefix sums of x[b,:,comp]: theta[b,l,m] = cx[b,l]*om0[m] + cy[b,l]*om1[m]
// ---------------------------------------------------------------------------
__global__ __launch_bounds__(512) void scan_kernel(const float* __restrict__ x,
                                                   void* __restrict__ wsv) {
  const int tid  = threadIdx.x;
  const int wave = tid >> 6, lane = tid & 63;
  const int b    = wave >> 1, comp = wave & 1;

  const float* xp = x + ((size_t)b * LL) * 2 + comp;
  double loc[8];
  double run = 0.0;
  #pragma unroll
  for (int e = 0; e < 8; ++e) {
    run += (double)xp[(lane * 8 + e) * 2];
    loc[e] = run;
  }
  double tot = run;
  #pragma unroll
  for (int off = 1; off < 64; off <<= 1) {
    const double o = __shfl_up(tot, off);
    if (lane >= off) tot += o;
  }
  const double excl = tot - run;
  float* cp = (float*)((char*)wsv + CXY_BYTE) + ((size_t)b * LL) * 2 + comp;
  #pragma unroll
  for (int e = 0; e < 8; ++e)
    cp[(lane * 8 + e) * 2] = (float)(excl + loc[e]);
}

// ---------------------------------------------------------------------------
// stage A = [S | z0] in fp64, plus St = S^T in fp32 for the combine kernel
// ---------------------------------------------------------------------------
__global__ __launch_bounds__(256) void stage_kernel(const float* __restrict__ S,
                                                    const float* __restrict__ z0,
                                                    void* __restrict__ wsv) {
  double* A  = (double*)((char*)wsv + A_BYTE);
  float*  St = (float*)((char*)wsv + ST_BYTE);
  const int idx = blockIdx.x * 256 + threadIdx.x;
  if (idx < N * N) {
    const int i = idx / N, j = idx - i * N;
    A[i * AP + j] = (double)S[idx];
    St[idx] = S[j * N + i];          // St[d][i] = S[i][d]; write coalesced
  } else {
    const int r = idx - N * N;
    if (r < N) A[r * AP + N] = (double)z0[r];
  }
}

// ---------------------------------------------------------------------------
// panel factor, round-6: REGISTER-RESIDENT row-parallel Jordan elimination.
//
// Round-2..4 evidence: LDS-resident Jordan stuck at ~38us/panel (per step:
// ~31 ds_read+fma+ds_write per thread + barrier ~= 1200cy). Now thread i
// holds row i's 32 panel entries in registers (r[32], fully static). Per
// step only the PIVOT row crosses LDS: 31 broadcast reads + 31 reg FMAs,
// zero LDS writes for non-pivot rows. The next pivot thread (pr+1) applies
// the step to itself, then publishes its trailing row + 1/diag into the
// double-buffered piv[] slot BEFORE the barrier (overlaps others' updates).
// U12 solve also register-resident (u[32], F11 broadcast from LDS).
// VGPR_Count is the residency check: expect 150-250; ~70-90 means spill.
// ---------------------------------------------------------------------------
__global__ __launch_bounds__(512, 1) void panel_factor_kernel(void* __restrict__ wsv,
                                                              int k0) {
  __shared__ double piv[2][NB];          // double-buffered pivot row trailing
  __shared__ double pinvs[2];            // 1/pivot, same parity
  __shared__ double F11s[NB][NB + 1];    // final L11\U11 block (for U12 solve)
  double* A    = (double*)((char*)wsv + A_BYTE);
  double* Pw   = (double*)((char*)wsv + PW_BYTE);
  double* U12w = (double*)((char*)wsv + U12_BYTE);
  const int tid = threadIdx.x;
  const int ct  = k0 + NB;
  const int tc2 = 258 - ct;              // trailing cols incl rhs

  // ---- stage my row's panel slice into registers (L2-resident A) ----
  double r[NB];
  if (tid < N) {
    const double* Ar = A + (size_t)tid * AP + k0;   // 16B-aligned (k0,AP even)
    #pragma unroll
    for (int c = 0; c < NB; c += 2) {
      const double2 v = *(const double2*)&Ar[c];
      r[c] = v.x; r[c + 1] = v.y;
    }
  }

  // ---- pre-step: pivot row k0 publishes itself ----
  if (tid == k0) {
    #pragma unroll
    for (int c = 0; c < NB; ++c) piv[0][c] = r[c];
    pinvs[0] = 1.0 / r[0];
  }
  __syncthreads();

  // ---- 32 Jordan steps, rows in registers, pivot row via LDS broadcast ----
  #pragma unroll
  for (int j = 0; j < NB; ++j) {
    const int pr = k0 + j;
    const int bsel = j & 1;
    if (tid < N && (tid < k0 || tid > pr)) {   // frozen: pivot rows k0..pr
      const double f = r[j] * pinvs[bsel];
      #pragma unroll
      for (int j2 = j + 1; j2 < NB; ++j2)
        r[j2] -= f * piv[bsel][j2];
      r[j] = f;
      if (j + 1 < NB && tid == pr + 1) {       // publish next pivot row
        #pragma unroll
        for (int c = 0; c < NB; ++c)
          if (c > j) piv[bsel ^ 1][c] = r[c];
        pinvs[bsel ^ 1] = 1.0 / r[j + 1];
      }
    }
    __syncthreads();
  }

  // ---- publish: pivot band -> F11s + A; other rows -> Pw (coalesced) ----
  if (tid < N) {
    if (tid >= k0 && tid < ct) {
      const int fr = tid - k0;
      #pragma unroll
      for (int c = 0; c < NB; ++c) {
        F11s[fr][c] = r[c];
        A[(size_t)tid * AP + k0 + c] = r[c];   // U11/L11 for finish kernel
      }
    } else {
      #pragma unroll
      for (int t = 0; t < NB; ++t)
        Pw[(size_t)t * N + tid] = r[t];
    }
  }
  __syncthreads();                             // F11s ready

  // ---- U12 forward solve: thread owns column, u[] in registers ----
  if (tid < tc2) {
    double u[NB];
    #pragma unroll
    for (int jr = 0; jr < NB; ++jr)
      u[jr] = A[(size_t)(k0 + jr) * AP + ct + tid];   // coalesced across tid
    #pragma unroll
    for (int jr = 1; jr < NB; ++jr) {
      double vv = u[jr];
      #pragma unroll
      for (int t = 0; t < jr; ++t)
        vv -= F11s[jr][t] * u[t];              // F11 broadcast, u in regs
      u[jr] = vv;
    }
    #pragma unroll
    for (int jr = 0; jr < NB; ++jr) {
      U12w[jr * 226 + tid] = u[jr];
      A[(size_t)(k0 + jr) * AP + ct + tid] = u[jr];
    }
  }
}

// ---------------------------------------------------------------------------
// panel update (grid-parallel Jordan rank-32 GEMM):
//   rows R = [0,k0) U [ct,N)  (225 rows, R-index rb; gr = rb<k0 ? rb : rb+32)
//   cols [ct, 258): A[gr][c] -= sum_t Pw[t][gr] * U12[t][c-ct]
// block tile = 32 rows x 64 cols; thread tile = 2x4.
// ---------------------------------------------------------------------------
__global__ __launch_bounds__(256) void panel_update_kernel(void* __restrict__ wsv,
                                                           int k0, int tc2) {
  __shared__ double Pl[NB][NB + 1];
  __shared__ __align__(16) double Ul[NB][66];
  double* A = (double*)((char*)wsv + A_BYTE);
  const double* Pw   = (const double*)((const char*)wsv + PW_BYTE);
  const double* U12w = (const double*)((const char*)wsv + U12_BYTE);
  const int tid = threadIdx.x;
  const int ct  = k0 + NB;
  const int rb0 = blockIdx.x * 32;
  const int c0  = blockIdx.y * 64;

  for (int i = tid; i < 32 * 32; i += 256) {
    const int t = i >> 5, rr = i & 31;
    const int rb = rb0 + rr;
    const int gr = (rb < k0) ? rb : rb + NB;
    Pl[t][rr] = (rb < 225) ? Pw[t * N + gr] : 0.0;
  }
  for (int i = tid; i < 32 * 64; i += 256) {
    const int t = i >> 6, c = i & 63;
    Ul[t][c] = (c0 + c < tc2) ? U12w[t * 226 + c0 + c] : 0.0;
  }
  __syncthreads();

  const int tr  = tid >> 4;          // 0..15 -> rows tr*2 .. +1
  const int tcx = (tid & 15) * 4;    // cols tcx .. +3
  double acc[2][4];
  #pragma unroll
  for (int rr = 0; rr < 2; ++rr) {
    const int rb = rb0 + tr * 2 + rr;
    const int gr = (rb < k0) ? rb : rb + NB;
    #pragma unroll
    for (int c = 0; c < 4; ++c)
      acc[rr][c] = (rb < 225 && (c0 + tcx + c) < tc2)
                 ? A[gr * AP + ct + c0 + tcx + c] : 0.0;
  }
  #pragma unroll
  for (int t = 0; t < NB; ++t) {
    const double p0 = Pl[t][tr * 2], p1 = Pl[t][tr * 2 + 1];
    const double2 u0 = *(const double2*)&Ul[t][tcx];
    const double2 u1 = *(const double2*)&Ul[t][tcx + 2];
    acc[0][0] -= p0 * u0.x; acc[0][1] -= p0 * u0.y;
    acc[0][2] -= p0 * u1.x; acc[0][3] -= p0 * u1.y;
    acc[1][0] -= p1 * u0.x; acc[1][1] -= p1 * u0.y;
    acc[1][2] -= p1 * u1.x; acc[1][3] -= p1 * u1.y;
  }
  #pragma unroll
  for (int rr = 0; rr < 2; ++rr) {
    const int rb = rb0 + tr * 2 + rr;
    const int gr = (rb < k0) ? rb : rb + NB;
    #pragma unroll
    for (int c = 0; c < 4; ++c)
      if (rb < 225 && (c0 + tcx + c) < tc2)
        A[gr * AP + ct + c0 + tcx + c] = acc[rr][c];
  }
}

// ---------------------------------------------------------------------------
// finish: x256 division, then 8 independent per-panel 32-step back-substs
// ---------------------------------------------------------------------------
__global__ __launch_bounds__(256) void finish_kernel(void* __restrict__ wsv) {
  __shared__ double xs[N];
  __shared__ double rr[256];
  double* A   = (double*)((char*)wsv + A_BYTE);
  float*  w0f = (float*)((char*)wsv + W0_BYTE);
  const int tid = threadIdx.x;
  if (tid == 0) xs[256] = A[256 * AP + 257] / A[256 * AP + 256];
  __syncthreads();
  const double x256 = xs[256];
  rr[tid] = A[tid * AP + 257] - A[tid * AP + 256] * x256;
  __syncthreads();
  const int fk0 = tid & ~31;
  const int fs  = tid & 31;
  for (int j = 31; j >= 0; --j) {
    if (fs == j) xs[fk0 + j] = rr[fk0 + j] / A[(fk0 + j) * AP + (fk0 + j)];
    __syncthreads();
    if (fs < j) rr[fk0 + fs] -= A[(fk0 + fs) * AP + (fk0 + j)] * xs[fk0 + j];
    __syncthreads();
  }
  w0f[tid] = (float)xs[tid];
  if (tid == 0) w0f[256] = (float)xs[256];
}

// ---------------------------------------------------------------------------
// combine: out[(b,l), i] = sum_d St[d, i] * W[(b,l), d]   (round-4 version)
// ---------------------------------------------------------------------------
#define NL 8
__global__ __launch_bounds__(320) void combine_kernel(const float* __restrict__ S,
                                                      const float* __restrict__ om,
                                                      const void* __restrict__ wsv,
                                                      float* __restrict__ out) {
  const int tid = threadIdx.x;
  const int b  = blockIdx.y;
  const int l0 = blockIdx.x * NL;
  const float* w0  = (const float*)((const char*)wsv + W0_BYTE);
  const float* cxy = (const float*)((const char*)wsv + CXY_BYTE);
  const float* St  = (const float*)((const char*)wsv + ST_BYTE);
  __shared__ __align__(16) float Wl[N][NL];
  __shared__ float omsh[2 * MM];
  __shared__ float cxs[NL], cys[NL];

  for (int idx = tid; idx < 2 * MM; idx += 320) omsh[idx] = om[idx];
  if (tid < NL) {
    cxs[tid] = cxy[((size_t)(b * LL) + l0 + tid) * 2];
    cys[tid] = cxy[((size_t)(b * LL) + l0 + tid) * 2 + 1];
  }
  __syncthreads();

  for (int idx = tid; idx < NL * N; idx += 320) {
    const int d = idx >> 3;
    const int r = idx & 7;
    float v;
    if (d == 0) {
      v = w0[0];
    } else {
      const int m = (d - 1) >> 1;
      const int pq = 2 * m + 1;
      const float t = cxs[r] * omsh[2 * m] + cys[r] * omsh[2 * m + 1];
      float s, c;
      sincosf(t, &s, &c);
      const float a0 = w0[pq], a1 = w0[pq + 1];
      v = (d & 1) ? (c * a0 - s * a1) : (s * a0 + c * a1);
    }
    Wl[d][r] = v;
  }
  __syncthreads();

  const int i = tid;
  if (i < N) {
    float acc[NL];
    #pragma unroll
    for (int r = 0; r < NL; ++r) acc[r] = 0.0f;
    #pragma unroll 8
    for (int d = 0; d < N; ++d) {
      const float stv = St[(size_t)d * N + i];
      const float4 wa = *(const float4*)&Wl[d][0];
      const float4 wb = *(const float4*)&Wl[d][4];
      acc[0] += stv * wa.x; acc[1] += stv * wa.y;
      acc[2] += stv * wa.z; acc[3] += stv * wa.w;
      acc[4] += stv * wb.x; acc[5] += stv * wb.y;
      acc[6] += stv * wb.z; acc[7] += stv * wb.w;
    }
    const size_t base = (size_t)(b * LL + l0) * N + i;
    #pragma unroll
    for (int r = 0; r < NL; ++r) out[base + (size_t)r * N] = acc[r];
    if (l0 + NL == LL) {
      out[(size_t)BB * LL * N + (size_t)b * N + i] = acc[NL - 1];
    }
  }
}

extern "C" void kernel_launch(void* const* d_in, const int* in_sizes, int n_in,
                              void* d_out, int out_size, void* d_ws, size_t ws_size,
                              hipStream_t stream) {
  const float* x  = (const float*)d_in[0];   // (B, L, 2)
  const float* z0 = (const float*)d_in[1];   // (D,)
  const float* om = (const float*)d_in[2];   // (M, 2)
  const float* S  = (const float*)d_in[3];   // (D, D)
  float* out = (float*)d_out;                // outputs (B,L,D) then z_final (B,D)

  hipLaunchKernelGGL(scan_kernel,  dim3(1),   dim3(512), 0, stream, x, d_ws);
  hipLaunchKernelGGL(stage_kernel, dim3(260), dim3(256), 0, stream, S, z0, d_ws);
  for (int p = 0; p < 8; ++p) {
    const int k0  = p * NB;
    const int tc2 = 258 - (k0 + NB);
    hipLaunchKernelGGL(panel_factor_kernel, dim3(1), dim3(512), 0, stream, d_ws, k0);
    hipLaunchKernelGGL(panel_update_kernel, dim3(8, (tc2 + 63) / 64), dim3(256),
                       0, stream, d_ws, k0, tc2);
  }
  hipLaunchKernelGGL(finish_kernel, dim3(1), dim3(256), 0, stream, d_ws);
  hipLaunchKernelGGL(combine_kernel, dim3(LL / NL, BB), dim3(320), 0, stream, S, om, d_ws, out);
}